// Round 8
// baseline (291.305 us; speedup 1.0000x reference)
//
#include <hip/hip_runtime.h>
#include <hip/hip_bf16.h>
#include <hip/hip_fp16.h>
#include <cstdint>
#include <cstddef>

// ---------------------------------------------------------------------------
// QuantizedMultiheadAttention  (N=4, T=2048, E=512, H=8, D=64)
//
// R8: attn idle-reduction. R7 attn was 41% idle (barrier drain of 16 DMA
// loads/thread + LDS-capped 2 blocks/CU). Changes:
//   - V fragments read DIRECT from global (wave-private tile, L2-hot),
//     issued inside the staging window so the existing vmcnt drain covers
//     them; K stays DMA-staged (8 loads/thread, halved).
//   - two-pass f32 epilogue reuses one 35KB LDS region -> LDS 36864 B.
//   - __launch_bounds__(256,3): 3 blocks/CU (was 2).
// Rest of pipeline unchanged from R7 (single-pass f16 everywhere).
// ---------------------------------------------------------------------------

typedef __attribute__((ext_vector_type(8))) _Float16 f16x8;
typedef __attribute__((ext_vector_type(2))) __fp16 hf16x2;   // cvt_pkrtz ret
typedef __attribute__((ext_vector_type(16))) float f32x16;
typedef __attribute__((ext_vector_type(4))) unsigned u32x4;
typedef unsigned short u16;

#define EL  4194304   // 4*2048*512 elements
#define WEL 262144    // 512*512

static __device__ __forceinline__ u16 f2h(float x) {
  _Float16 h = (_Float16)x;                      // v_cvt_f16_f32 (RNE)
  return __builtin_bit_cast(u16, h);
}
static __device__ __forceinline__ unsigned pkh2(float a, float b) {
  hf16x2 p = __builtin_amdgcn_cvt_pkrtz(a, b);   // packed f16, a=low b=high
  return __builtin_bit_cast(unsigned, p);
}
static __device__ __forceinline__ void gl_lds16(const void* g, void* l) {
  __builtin_amdgcn_global_load_lds(
      (__attribute__((address_space(1))) void*)g,
      (__attribute__((address_space(3))) void*)l, 16, 0, 0);
}

// ---------------------------------------------------------------------------
// prep_all: fp32 -> f16 for [query, keys, values, Wq, Wk, Wv, Wo]
// ---------------------------------------------------------------------------
struct PrepAllArgs { const float* src[7]; };

__global__ __launch_bounds__(256) void prep_all_kernel(PrepAllArgs a,
                                                       u16* __restrict__ dst)
{
  const int i = blockIdx.x * 256 + threadIdx.x;   // quad index
  const float* src; int off;
  if (i < 3145728) {                              // 3 * EL/4, EL/4 = 2^20
    const int m = i >> 20; off = i & 1048575;
    src = (m == 0) ? a.src[0] : (m == 1) ? a.src[1] : a.src[2];
  } else {                                        // 4 * WEL/4, WEL/4 = 2^16
    const int j = i - 3145728; const int w = j >> 16; off = j & 65535;
    src = (w == 0) ? a.src[3] : (w == 1) ? a.src[4]
        : (w == 2) ? a.src[5] : a.src[6];
  }
  const float4 v = ((const float4*)src)[off];
  ushort4 o;
  o.x = f2h(v.x); o.y = f2h(v.y); o.z = f2h(v.z); o.w = f2h(v.w);
  ((ushort4*)dst)[i] = o;
}

// ---------------------------------------------------------------------------
// proj: C = quantize(X@W^T + b), single-pass f16, 128x128 tile, BK=64.
// ---------------------------------------------------------------------------
struct ProjArgs {
  const u16* X[3]; const u16* W[3]; const float* bias[3];
  u16* dst[3]; int trans[3];
};

__global__ __launch_bounds__(256, 3) void proj_kernel(ProjArgs args,
    const float* __restrict__ bparam, const float* __restrict__ eparam)
{
  __shared__ u16 sm[17408];            // staging 32 KB; trans-epilogue 34816 B
  u16* const As = sm;                  // bytes [0, 16384)
  u16* const Bs = sm + 8192;           // bytes [16384, 32768)

  const int z = blockIdx.z;
  const u16* __restrict__ X = args.X[z];
  const u16* __restrict__ W = args.W[z];
  const float* __restrict__ bias = args.bias[z];
  u16* __restrict__ dst = args.dst[z];
  const int trans = args.trans[z];

  const int tid  = threadIdx.x;
  const int lane = tid & 63;
  const int wave = tid >> 6;
  const int lam  = lane & 31;
  const int hl   = lane >> 5;
  const int wm   = wave & 1;
  const int wn   = wave >> 1;
  const int mbase = blockIdx.x * 128;
  const int nbase = blockIdx.y * 128;

  const int srow = tid >> 3;                       // 0..31
  const int sj   = (tid & 7) ^ (srow & 7);
  const u16* gA = X + (size_t)(mbase + srow) * 512 + sj * 8;
  const u16* gB = W + (size_t)(nbase + srow) * 512 + sj * 8;

  int offA[2][4], offB[2][4];
#pragma unroll
  for (int f = 0; f < 2; ++f)
#pragma unroll
    for (int kk = 0; kk < 4; ++kk) {
      const int c = 2 * kk + hl;
      const int m = wm * 64 + f * 32 + lam;
      offA[f][kk] = m * 128 + ((c ^ (m & 7)) * 16);
      const int nn = wn * 64 + f * 32 + lam;
      offB[f][kk] = nn * 128 + ((c ^ (nn & 7)) * 16);
    }

  f32x16 acc[2][2];
#pragma unroll
  for (int a = 0; a < 2; ++a)
#pragma unroll
    for (int b = 0; b < 2; ++b)
#pragma unroll
      for (int i = 0; i < 16; ++i) acc[a][b][i] = 0.f;

  for (int kt = 0; kt < 512; kt += 64) {
    __syncthreads();                   // prior frag reads done
#pragma unroll
    for (int t = 0; t < 4; ++t) {
      gl_lds16(gA + kt + t * 32 * 512, (char*)As + tid * 16 + t * 4096);
      gl_lds16(gB + kt + t * 32 * 512, (char*)Bs + tid * 16 + t * 4096);
    }
    __syncthreads();                   // staging complete

    f16x8 fA[2][4], fB[2][4];
#pragma unroll
    for (int f = 0; f < 2; ++f)
#pragma unroll
      for (int kk = 0; kk < 4; ++kk) {
        fA[f][kk] = *(const f16x8*)((const char*)As + offA[f][kk]);
        fB[f][kk] = *(const f16x8*)((const char*)Bs + offB[f][kk]);
      }
#pragma unroll
    for (int mf = 0; mf < 2; ++mf)
#pragma unroll
      for (int nf = 0; nf < 2; ++nf)
#pragma unroll
        for (int kk = 0; kk < 4; ++kk)
          acc[mf][nf] = __builtin_amdgcn_mfma_f32_32x32x16_f16(
              fA[mf][kk], fB[nf][kk], acc[mf][nf], 0, 0, 0);
  }

  const float bq   = fminf(fmaxf(bparam[0], 1.0f), 8.0f);
  const float e    = eparam[0];
  const float s    = exp2f(e);
  const float invs = exp2f(-e);
  const float qlo  = -exp2f(bq - 1.0f);
  const float qhi  = exp2f(bq - 1.0f) - 1.0f;
  const int nidx = mbase >> 11;        // batch
  const int tb   = mbase & 2047;       // t base
  const int hb   = nbase >> 6;         // head base

  if (!trans) {
#pragma unroll
    for (int mf = 0; mf < 2; ++mf)
#pragma unroll
      for (int nf = 0; nf < 2; ++nf)
#pragma unroll
        for (int reg = 0; reg < 16; ++reg) {
          int col = wn * 64 + nf * 32 + lam;
          int row = wm * 64 + mf * 32 + (reg & 3) + 8 * (reg >> 2) + 4 * hl;
          float v = acc[mf][nf][reg] + bias[nbase + col];
          float qv = floorf(fminf(fmaxf(v * invs, qlo), qhi)) * s;
          dst[((size_t)(nidx * 8 + hb + (col >> 6)) * 2048 + tb + row) * 64 +
              (col & 63)] = f2h(qv);
        }
  } else {
    __syncthreads();
#pragma unroll
    for (int mf = 0; mf < 2; ++mf)
#pragma unroll
      for (int nf = 0; nf < 2; ++nf)
#pragma unroll
        for (int reg = 0; reg < 16; ++reg) {
          int col = wn * 64 + nf * 32 + lam;
          int row = wm * 64 + mf * 32 + (reg & 3) + 8 * (reg >> 2) + 4 * hl;
          float v = acc[mf][nf][reg] + bias[nbase + col];
          float qv = floorf(fminf(fmaxf(v * invs, qlo), qhi)) * s;
          sm[col * 136 + row] = f2h(qv);
        }
    __syncthreads();
    const int r = tid >> 1, half = tid & 1;
    const u16* sp = sm + r * 136 + half * 64;
    u16* gp = dst + ((size_t)(nidx * 8 + hb + (r >> 6)) * 64 + (r & 63)) * 2048 +
              tb + half * 64;
#pragma unroll
    for (int i = 0; i < 8; ++i)
      *(uint4*)(gp + i * 8) = *(const uint4*)(sp + i * 8);
  }
}

// ---------------------------------------------------------------------------
// attn: key-split waves; K DMA-staged (wave-private 64x64 tile, swizzled),
// V fragments direct from global inside the staging window, two-pass f32
// epilogue. LDS 36864 B; 3 blocks/CU.
// ---------------------------------------------------------------------------
__global__ __launch_bounds__(256, 3) void attn_kernel(
    const u16* __restrict__ qbuf, const u16* __restrict__ kbuf,
    const u16* __restrict__ vtbuf, u16* __restrict__ ctx)
{
  __shared__ u16 sm[18432];            // 36864 B: K staging 32KB / epilogue
  char* const smc = (char*)sm;

  const int tid  = threadIdx.x;
  const int wave = tid >> 6;
  const int lane = tid & 63;
  const int lam  = lane & 31;
  const int hl   = lane >> 5;
  const int qt = blockIdx.x, hd = blockIdx.y, n = blockIdx.z;
  const int nh = n * 8 + hd;
  const int qbase = qt * 64;

  const u16* Qp = qbuf + ((size_t)nh * 2048 + qbase) * 64;
  const u16* Kp = kbuf + (size_t)nh * 131072;
  const u16* Vp = vtbuf + (size_t)nh * 131072;

  f16x8 qf[2][4];                      // B-operand: B[n=q][k=d]
#pragma unroll
  for (int qb = 0; qb < 2; ++qb)
#pragma unroll
    for (int dk = 0; dk < 4; ++dk)
      qf[qb][dk] = *(const f16x8*)(Qp + (qb * 32 + lam) * 64 + dk * 16 + hl * 8);

  const float sc = (float)(1.4426950408889634 / 22.627416997969522); // log2e/sqrt(512)

  // K staging: slot s in {tid, tid+256}; row=s>>3, chunk=(s&7)^(row&7)
  const int r0 = tid >> 3;
  const int j0 = (tid & 7) ^ (r0 & 7);
  const u16* gK0 = Kp + (size_t)r0 * 64 + j0 * 8;
  const u16* gK1 = Kp + (size_t)(r0 + 32) * 64 + j0 * 8;

  int offK[2][4];
#pragma unroll
  for (int kf = 0; kf < 2; ++kf)
#pragma unroll
    for (int dk = 0; dk < 4; ++dk)
      offK[kf][dk] = wave * 8192 + (kf * 32 + lam) * 128 +
                     (((2 * dk + hl) ^ (lam & 7)) * 16);

  // V direct-from-global fragment base (wave-private 64-key tile)
  const u16* gV0 = Vp + (size_t)lam * 2048 + wave * 64 + hl * 8;
  const u16* gV1 = Vp + (size_t)(32 + lam) * 2048 + wave * 64 + hl * 8;

  float l_acc[2] = {0.f, 0.f};
  f32x16 O[2][2];
#pragma unroll
  for (int a = 0; a < 2; ++a)
#pragma unroll
    for (int b = 0; b < 2; ++b)
#pragma unroll
      for (int i = 0; i < 16; ++i) O[a][b][i] = 0.f;

  for (int kt = 0; kt < 2048; kt += 256) {
    __syncthreads();                   // prior tile's K frag reads done
#pragma unroll
    for (int wt = 0; wt < 4; ++wt) {
      const size_t ko = (size_t)(kt + wt * 64) * 64;
      gl_lds16(gK0 + ko, smc + wt * 8192 + tid * 16);
      gl_lds16(gK1 + ko, smc + wt * 8192 + tid * 16 + 4096);
    }
    // V fragments: direct global loads; the barrier's vmcnt drain covers them
    f16x8 Vf[2][4];
#pragma unroll
    for (int kk = 0; kk < 4; ++kk) {
      Vf[0][kk] = *(const f16x8*)(gV0 + kt + kk * 16);
      Vf[1][kk] = *(const f16x8*)(gV1 + kt + kk * 16);
    }
    __syncthreads();                   // staging + V loads complete

#pragma unroll
    for (int kf = 0; kf < 2; ++kf) {
      f16x8 Kf[4];
#pragma unroll
      for (int dk = 0; dk < 4; ++dk)
        Kf[dk] = *(const f16x8*)(smc + offK[kf][dk]);

#pragma unroll
      for (int qb = 0; qb < 2; ++qb) {
        f32x16 S;
#pragma unroll
        for (int i = 0; i < 16; ++i) S[i] = 0.f;
#pragma unroll
        for (int dk = 0; dk < 4; ++dk)
          S = __builtin_amdgcn_mfma_f32_32x32x16_f16(Kf[dk], qf[qb][dk],
                                                     S, 0, 0, 0);
        // no-max softmax; lane (lam,hl): q-row qb*32+lam, key groups g&1==hl
        unsigned pk[4][2];
#pragma unroll
        for (int gh = 0; gh < 4; ++gh) {
          float p0 = __builtin_amdgcn_exp2f(S[4 * gh + 0] * sc);
          float p1 = __builtin_amdgcn_exp2f(S[4 * gh + 1] * sc);
          float p2 = __builtin_amdgcn_exp2f(S[4 * gh + 2] * sc);
          float p3 = __builtin_amdgcn_exp2f(S[4 * gh + 3] * sc);
          l_acc[qb] += (p0 + p1) + (p2 + p3);
          pk[gh][0] = pkh2(p0, p1);
          pk[gh][1] = pkh2(p2, p3);
        }
        // C->A transform: exchange complementary group with partner (^32)
        f16x8 pfrag[2];
#pragma unroll
        for (int kkl = 0; kkl < 2; ++kkl) {
          unsigned s0 = hl ? pk[2 * kkl][0] : pk[2 * kkl + 1][0];
          unsigned s1 = hl ? pk[2 * kkl][1] : pk[2 * kkl + 1][1];
          unsigned o0 = hl ? pk[2 * kkl + 1][0] : pk[2 * kkl][0];
          unsigned o1 = hl ? pk[2 * kkl + 1][1] : pk[2 * kkl][1];
          unsigned rr0 = (unsigned)__shfl_xor((int)s0, 32);
          unsigned rr1 = (unsigned)__shfl_xor((int)s1, 32);
          u32x4 f;
          f[0] = hl ? rr0 : o0;
          f[1] = hl ? rr1 : o1;
          f[2] = hl ? o0 : rr0;
          f[3] = hl ? o1 : rr1;
          pfrag[kkl] = __builtin_bit_cast(f16x8, f);
        }
#pragma unroll
        for (int nf = 0; nf < 2; ++nf)
#pragma unroll
          for (int kkl = 0; kkl < 2; ++kkl)
            O[qb][nf] = __builtin_amdgcn_mfma_f32_32x32x16_f16(
                pfrag[kkl], Vf[nf][2 * kf + kkl], O[qb][nf], 0, 0, 0);
      }
    }
  }

  // ---- epilogue: two-pass cross-wave O reduction (f32), normalize ----
  l_acc[0] += __shfl_xor(l_acc[0], 32);
  l_acc[1] += __shfl_xor(l_acc[1], 32);
  __syncthreads();                     // all waves done with K region
  float* lred = (float*)(smc + 35840); // 256 f32
  if (hl == 0) {
    lred[wave * 64 + lam]      = l_acc[0];
    lred[wave * 64 + 32 + lam] = l_acc[1];
  }
  float* Ow = (float*)(smc + wave * 8960);  // 64 rows x 35 f32 per wave
  float rinv = 0.f;
  const int q  = tid >> 2;
  const int sg = tid & 3;
#pragma unroll
  for (int nf = 0; nf < 2; ++nf) {
    if (nf) __syncthreads();           // pass-0 reads done before overwrite
#pragma unroll
    for (int qb = 0; qb < 2; ++qb)
#pragma unroll
      for (int r = 0; r < 16; ++r) {
        int qrow = qb * 32 + (r & 3) + 8 * (r >> 2) + 4 * hl;
        Ow[qrow * 35 + lam] = O[qb][nf][r];
      }
    __syncthreads();
    if (nf == 0) {
      const float lsum = lred[q] + lred[64 + q] + lred[128 + q] + lred[192 + q];
      rinv = 1.0f / lsum;
    }
    float acc[8];
    {
      const char* b0 = smc + q * 140 + sg * 32;
      const float4 v0 = *(const float4*)(b0);
      const float4 v1 = *(const float4*)(b0 + 16);
      acc[0]=v0.x; acc[1]=v0.y; acc[2]=v0.z; acc[3]=v0.w;
      acc[4]=v1.x; acc[5]=v1.y; acc[6]=v1.z; acc[7]=v1.w;
    }
#pragma unroll
    for (int w = 1; w < 4; ++w) {
      const char* b = smc + w * 8960 + q * 140 + sg * 32;
      const float4 v0 = *(const float4*)(b);
      const float4 v1 = *(const float4*)(b + 16);
      acc[0]+=v0.x; acc[1]+=v0.y; acc[2]+=v0.z; acc[3]+=v0.w;
      acc[4]+=v1.x; acc[5]+=v1.y; acc[6]+=v1.z; acc[7]+=v1.w;
    }
    unsigned outp[4];
#pragma unroll
    for (int i = 0; i < 4; ++i)
      outp[i] = pkh2(acc[2 * i] * rinv, acc[2 * i + 1] * rinv);
    u16* cp = ctx + ((size_t)n * 2048 + qbase + q) * 512 + hd * 64 +
              nf * 32 + sg * 8;
    *(uint4*)cp = *(const uint4*)&outp[0];
  }
}

// ---------------------------------------------------------------------------
// outproj: out = ctx @ Wo^T + bo, f16, 64x128 tile, BK=64 (512 blocks)
// ---------------------------------------------------------------------------
__global__ __launch_bounds__(256) void outproj_kernel(
    const u16* __restrict__ ctxb, const u16* __restrict__ Wof,
    const float* __restrict__ bias, float* __restrict__ out)
{
  __shared__ u16 sm[12288];            // A 8KB | B 16KB
  u16* const As = sm;
  u16* const Bs = sm + 4096;

  const int tid  = threadIdx.x;
  const int lane = tid & 63;
  const int wave = tid >> 6;
  const int lam  = lane & 31;
  const int hl   = lane >> 5;
  const int wm   = wave & 1;
  const int wn   = wave >> 1;
  const int mbase = blockIdx.x * 64;
  const int nbase = blockIdx.y * 128;

  const int srow = tid >> 3;
  const int sj   = (tid & 7) ^ (srow & 7);
  const u16* gA = ctxb + (size_t)(mbase + srow) * 512 + sj * 8;
  const u16* gB = Wof  + (size_t)(nbase + srow) * 512 + sj * 8;

  int offA[4], offB[2][4];
#pragma unroll
  for (int kk = 0; kk < 4; ++kk) {
    const int c = 2 * kk + hl;
    const int m = wm * 32 + lam;
    offA[kk] = m * 128 + ((c ^ (m & 7)) * 16);
#pragma unroll
    for (int f = 0; f < 2; ++f) {
      const int nn = wn * 64 + f * 32 + lam;
      offB[f][kk] = nn * 128 + ((c ^ (nn & 7)) * 16);
    }
  }

  f32x16 acc[2];
#pragma unroll
  for (int a = 0; a < 2; ++a)
#pragma unroll
    for (int i = 0; i < 16; ++i) acc[a][i] = 0.f;

  for (int kt = 0; kt < 512; kt += 64) {
    __syncthreads();
#pragma unroll
    for (int t = 0; t < 2; ++t)
      gl_lds16(gA + kt + t * 32 * 512, (char*)As + tid * 16 + t * 4096);
#pragma unroll
    for (int t = 0; t < 4; ++t)
      gl_lds16(gB + kt + t * 32 * 512, (char*)Bs + tid * 16 + t * 4096);
    __syncthreads();

    f16x8 fA[4], fB[2][4];
#pragma unroll
    for (int kk = 0; kk < 4; ++kk) {
      fA[kk] = *(const f16x8*)((const char*)As + offA[kk]);
#pragma unroll
      for (int f = 0; f < 2; ++f)
        fB[f][kk] = *(const f16x8*)((const char*)Bs + offB[f][kk]);
    }
#pragma unroll
    for (int nf = 0; nf < 2; ++nf)
#pragma unroll
      for (int kk = 0; kk < 4; ++kk)
        acc[nf] = __builtin_amdgcn_mfma_f32_32x32x16_f16(
            fA[kk], fB[nf][kk], acc[nf], 0, 0, 0);
  }

#pragma unroll
  for (int nf = 0; nf < 2; ++nf)
#pragma unroll
    for (int reg = 0; reg < 16; ++reg) {
      int col = nbase + wn * 64 + nf * 32 + lam;
      int row = mbase + wm * 32 + (reg & 3) + 8 * (reg >> 2) + 4 * hl;
      out[(size_t)row * 512 + col] = acc[nf][reg] + bias[col];
    }
}

// ---------------------------------------------------------------------------
extern "C" void kernel_launch(void* const* d_in, const int* in_sizes, int n_in,
                              void* d_out, int out_size, void* d_ws, size_t ws_size,
                              hipStream_t stream) {
  (void)in_sizes; (void)n_in; (void)out_size; (void)ws_size;
  const float* values = (const float*)d_in[0];
  const float* keys   = (const float*)d_in[1];
  const float* query  = (const float*)d_in[2];
  const float* Wq = (const float*)d_in[3];  const float* bq = (const float*)d_in[4];
  const float* Wk = (const float*)d_in[5];  const float* bk = (const float*)d_in[6];
  const float* Wv = (const float*)d_in[7];  const float* bv = (const float*)d_in[8];
  const float* Wo = (const float*)d_in[9];  const float* bo = (const float*)d_in[10];
  const float* bp = (const float*)d_in[11]; const float* ep = (const float*)d_in[12];

  u16* ws    = (u16*)d_ws;
  u16* qbuf  = ws;
  u16* kbuf  = ws + (size_t)EL;
  u16* vtbuf = ws + (size_t)2 * EL;
  u16* ctx   = ws + (size_t)3 * EL;
  u16* xwf   = ws + (size_t)4 * EL;

  PrepAllArgs pa;
  pa.src[0] = query; pa.src[1] = keys; pa.src[2] = values;
  pa.src[3] = Wq; pa.src[4] = Wk; pa.src[5] = Wv; pa.src[6] = Wo;
  prep_all_kernel<<<13312, 256, 0, stream>>>(pa, xwf);

  const float* Bsrc[3] = {bq, bk, bv};
  u16* Dst[3] = {qbuf, kbuf, vtbuf};
  ProjArgs a;
  for (int m = 0; m < 3; ++m) {
    a.X[m] = xwf + (size_t)m * EL;
    a.W[m] = xwf + (size_t)3 * EL + (size_t)m * WEL;
    a.bias[m] = Bsrc[m]; a.dst[m] = Dst[m]; a.trans[m] = (m == 2);
  }
  proj_kernel<<<dim3(64, 4, 3), 256, 0, stream>>>(a, bp, ep);

  attn_kernel<<<dim3(32, 8, 4), 256, 0, stream>>>(qbuf, kbuf, vtbuf, ctx);
  outproj_kernel<<<dim3(128, 4), 256, 0, stream>>>(
      ctx, xwf + (size_t)3 * EL + (size_t)3 * WEL, bo, (float*)d_out);
}